// Round 3
// baseline (738.642 us; speedup 1.0000x reference)
//
#include <hip/hip_runtime.h>
#include <hip/hip_bf16.h>

typedef __hip_bfloat16 bf16;
typedef __attribute__((ext_vector_type(8))) short bf16x8;
typedef __attribute__((ext_vector_type(4))) float f32x4;

#define SEQ     2048
#define DMODEL  1024
#define DINNER  2048
#define NBATCH  4
#define NROWS   (NBATCH * SEQ)   // 8192
#define DSTATE  16
#define NCHUNK  16
#define CHUNK   128              // SEQ / NCHUNK

__device__ __forceinline__ float b2f(short s) {
    union { unsigned u; float f; } c;
    c.u = ((unsigned)(unsigned short)s) << 16;
    return c.f;
}

// async global->LDS direct copy, 16B per lane. LDS dest must be wave-uniform
// base (HW adds lane*16). CK-style addrspace casts via uintptr_t.
__device__ __forceinline__ void async16(const bf16* g, bf16* l) {
    auto gp = reinterpret_cast<const __attribute__((address_space(1))) unsigned*>(
        reinterpret_cast<uintptr_t>(g));
    auto lp = reinterpret_cast<__attribute__((address_space(3))) unsigned*>(
        reinterpret_cast<uintptr_t>(l));
    __builtin_amdgcn_global_load_lds(gp, lp, 16, 0, 0);
}

// ---------------------------------------------------------------------------
// Fused weight-prep kernel: one dispatch does all 4 transposes + the x cast.
//   [0,     8192): cast x (fp32->bf16), 4 elems/thread
//   [8192, 12288): W_in  (1024x4096) -> WinT  (4096x1024)
//   [12288,16384): W_dt  (2048x2048) -> WcombT rows 0..2047
//   [16384,16640): W_x   (2048x32)   -> WcombT rows 2048..2175 (pad 128)
//   [16640,18688): W_out (2048x1024) -> WoutT (1024x2048)
// WcombT is allocated with 2304 rows; rows 2176..2303 stay uninitialized and
// only feed MFMA frags whose outputs are discarded in the guarded epilogue.
// ---------------------------------------------------------------------------
__device__ __forceinline__ void transpose_tile(
    const float* __restrict__ W, bf16* __restrict__ WT,
    int K, int N, int Npad, int bx, int by)
{
    __shared__ float tile[32][33];
    const int tx = threadIdx.x & 31, ty = threadIdx.x >> 5;   // 32 x 8
    const int x = bx * 32 + tx;           // N index
#pragma unroll
    for (int i = 0; i < 32; i += 8) {
        int y = by * 32 + ty + i;         // K index
        tile[ty + i][tx] = (x < N && y < K) ? W[(size_t)y * N + x] : 0.f;
    }
    __syncthreads();
    const int k = by * 32 + tx;
#pragma unroll
    for (int i = 0; i < 32; i += 8) {
        int n = bx * 32 + ty + i;
        if (n < Npad && k < K)
            WT[(size_t)n * K + k] = __float2bfloat16(tile[tx][ty + i]);
    }
}

__global__ __launch_bounds__(256)
void prep(const float* __restrict__ x,     const float* __restrict__ W_in,
          const float* __restrict__ W_dt,  const float* __restrict__ W_x,
          const float* __restrict__ W_out, bf16* __restrict__ x_bf,
          bf16* __restrict__ WinT, bf16* __restrict__ WcombT,
          bf16* __restrict__ WoutT)
{
    const int bid = blockIdx.x;
    if (bid < 8192) {
        int i = bid * 256 + threadIdx.x;          // x cast: 8.4M elems / 4
        float4 v = *(const float4*)(x + (size_t)i * 4);
        __align__(8) bf16 o[4] = { __float2bfloat16(v.x), __float2bfloat16(v.y),
                                   __float2bfloat16(v.z), __float2bfloat16(v.w) };
        *(uint2*)(x_bf + (size_t)i * 4) = *(uint2*)o;
    } else if (bid < 12288) {
        int t = bid - 8192;                       // W_in: 128 x 32 tiles
        transpose_tile(W_in, WinT, 1024, 4096, 4096, t & 127, t >> 7);
    } else if (bid < 16384) {
        int t = bid - 12288;                      // W_dt: 64 x 64 tiles
        transpose_tile(W_dt, WcombT, 2048, 2048, 2048, t & 63, t >> 6);
    } else if (bid < 16640) {
        int t = bid - 16384;                      // W_x: 4 x 64 tiles
        transpose_tile(W_x, WcombT + (size_t)2048 * 2048, 2048, 32, 128,
                       t & 3, t >> 2);
    } else {
        int t = bid - 16640;                      // W_out: 32 x 64 tiles
        transpose_tile(W_out, WoutT, 2048, 1024, 1024, t & 31, t >> 5);
    }
}

// ---------------------------------------------------------------------------
// 256x256 GEMM: C[M,N] = A[M,K] @ B^T[N,K]  (bf16 in, fp32 accum).
// R10: 2-phase double-buffered global_load_lds at 256^2/BK=64, 512 threads
// (8 waves, 2M x 4N, 128x64 output each, 8x4 MFMA frags, 64 MFMA/wave/tile).
// Rationale: R7/R8/R9 all ~160-177us at 128^2 regardless of staging style ->
// the 128^2/BK=32 tile lacks compute per iteration to cover the vmcnt(0)
// drain (catalog m233: stage+vmcnt+barrier = 72% of 2-phase time). 256^2
// doubles FLOP/staged-byte, halves iters, quadruples per-barrier compute.
// Catalog: 256^2+2ph = 666-682 TF refcheck'd @K=1024 (m230/m248v2).
// LDS 128KB static (2 bufs x (A 32KB + B 32KB)) -> 1 block/CU; plain-HIP
// 128KB LDS proven on gfx950 (m194-m201). T2 swizzle + T5 setprio skipped:
// both measured null on 2-phase structures.
// MODE 2: store bf16.  MODE 3: merged dt/bdt epilogue (guarded for N-pad).
// ---------------------------------------------------------------------------
template <int MODE>
__global__ __launch_bounds__(512, 2)
void gemm256(const bf16* __restrict__ A, int lda, const bf16* __restrict__ BT,
             int ldb, float* __restrict__ Cf, bf16* __restrict__ Cb, int ldc,
             const float* __restrict__ bias, int K)
{
    __shared__ __align__(16) bf16 As[2][256 * 64];
    __shared__ __align__(16) bf16 Bs[2][256 * 64];
    const int tid  = threadIdx.x;
    const int lane = tid & 63;
    const int wave = tid >> 6;          // 0..7

    // ---- group-of-8 m-panel swizzle (L2/L3 reuse) ----
    const int gx = gridDim.x, gy = gridDim.y;
    int lin = blockIdx.y * gx + blockIdx.x;
    const int per = 8 * gx;
    int g   = lin / per;
    int rem = lin - g * per;
    int rows = min(8, gy - g * 8);
    const int by = g * 8 + rem % rows;
    const int bx = rem / rows;

    const int m0 = by * 256;
    const int n0 = bx * 256;
    const int wm = (wave >> 2) * 128;   // 0 or 128
    const int wn = (wave & 3) * 64;     // 0,64,128,192

    f32x4 acc[8][4];
#pragma unroll
    for (int i = 0; i < 8; ++i)
#pragma unroll
        for (int j = 0; j < 4; ++j) acc[i][j] = (f32x4){0.f, 0.f, 0.f, 0.f};

    // staging: tile = 256 rows x 64 cols bf16 = 2048 16B-chunks, row-major.
    // chunk c -> global row c>>3, elem (c&7)*8; LDS elem c*8 (linear).
    // issue q in [0,4): this thread's chunk = q*512 + tid; within a wave the
    // 64 lanes cover chunks [q*512 + wave*64, +64) -> LDS base q*4096+wave*512
    // (wave-uniform, HW adds lane*16B).
    const bf16* pa[4];
    const bf16* pb[4];
#pragma unroll
    for (int q = 0; q < 4; ++q) {
        int c = q * 512 + tid;
        int r = c >> 3, e = (c & 7) * 8;
        pa[q] = A  + (size_t)(m0 + r) * lda + e;
        pb[q] = BT + (size_t)(n0 + r) * ldb + e;
    }

    const int arow = lane & 15;
    const int akq  = (lane >> 4) * 8;
    const int KT = K >> 6;              // 16 (K=1024) or 32 (K=2048): even

    auto STAGE = [&](int buf, int kt) {
        const int k0 = kt * 64;
#pragma unroll
        for (int q = 0; q < 4; ++q)
            async16(pa[q] + k0, &As[buf][q * 4096 + wave * 512]);
#pragma unroll
        for (int q = 0; q < 4; ++q)
            async16(pb[q] + k0, &Bs[buf][q * 4096 + wave * 512]);
    };
    auto COMPUTE = [&](int buf) {
#pragma unroll
        for (int ks = 0; ks < 2; ++ks) {
            bf16x8 bfr[4];
#pragma unroll
            for (int j = 0; j < 4; ++j)
                bfr[j] = *(const bf16x8*)(
                    &Bs[buf][(wn + j * 16 + arow) * 64 + ks * 32 + akq]);
#pragma unroll
            for (int i = 0; i < 8; ++i) {
                bf16x8 af = *(const bf16x8*)(
                    &As[buf][(wm + i * 16 + arow) * 64 + ks * 32 + akq]);
#pragma unroll
                for (int j = 0; j < 4; ++j)
                    acc[i][j] = __builtin_amdgcn_mfma_f32_16x16x32_bf16(
                        af, bfr[j], acc[i][j], 0, 0, 0);
            }
        }
    };

    // prologue: stage tile 0; __syncthreads() = vmcnt(0)+barrier publishes it
    STAGE(0, 0);
    __syncthreads();

    for (int kt = 0; kt < KT; kt += 2) {
        STAGE(1, kt + 1);                // issue-ahead into buf1
        COMPUTE(0);
        __syncthreads();                 // buf1 landed; all done reading buf0
        if (kt + 2 < KT) STAGE(0, kt + 2);
        COMPUTE(1);
        __syncthreads();                 // buf0 landed; all done reading buf1
    }

    // epilogue: C/D layout col = lane&15, row = (lane>>4)*4 + reg
    const int rbase = (lane >> 4) * 4;
    const int cbase = lane & 15;
#pragma unroll
    for (int i = 0; i < 8; ++i) {
        int row = m0 + wm + i * 16 + rbase;
#pragma unroll
        for (int j = 0; j < 4; ++j) {
            int col = n0 + wn + j * 16 + cbase;
#pragma unroll
            for (int r = 0; r < 4; ++r) {
                float v = acc[i][j][r];
                if (MODE == 2) {
                    Cb[(size_t)(row + r) * ldc + col] = __float2bfloat16(v);
                } else {   // MODE 3: dt cols [0,2048), bdt [2048,2176), pad discard
                    if (col < DINNER) {
                        float v2 = v + bias[col];
                        float sp = (v2 > 20.f) ? v2 : log1pf(__expf(v2));
                        Cb[(size_t)(row + r) * ldc + col] = __float2bfloat16(sp);
                    } else if (col < DINNER + 128) {
                        Cf[(size_t)(row + r) * 128 + (col - DINNER)] = v;
                    }
                }
            }
        }
    }
}

// ---------------------------------------------------------------------------
// 128x128 GEMM (kept for GEMM_out, N=1024: 512 blocks vs 128 at 256^2).
// R9 structure: double-buffered global_load_lds, issue-ahead, 1 barrier/tile.
// MODE 0: store fp32.
// ---------------------------------------------------------------------------
template <int MODE>
__global__ __launch_bounds__(256, 2)
void gemm_bt(const bf16* __restrict__ A, int lda, const bf16* __restrict__ BT,
             int ldb, float* __restrict__ Cf, bf16* __restrict__ Cb, int ldc,
             const float* __restrict__ bias, int K)
{
    __shared__ __align__(16) bf16 As[2][128 * 32];
    __shared__ __align__(16) bf16 Bs[2][128 * 32];
    const int tid  = threadIdx.x;
    const int lane = tid & 63;
    const int wave = tid >> 6;

    const int gx = gridDim.x, gy = gridDim.y;
    int lin = blockIdx.y * gx + blockIdx.x;
    const int per = 8 * gx;
    int g   = lin / per;
    int rem = lin - g * per;
    int rows = min(8, gy - g * 8);
    const int by = g * 8 + rem % rows;
    const int bx = rem / rows;

    const int m0 = by * 128;
    const int n0 = bx * 128;
    const int wm = (wave & 1) * 64;
    const int wn = (wave >> 1) * 64;

    f32x4 acc[4][4];
#pragma unroll
    for (int i = 0; i < 4; ++i)
#pragma unroll
        for (int j = 0; j < 4; ++j) acc[i][j] = (f32x4){0.f, 0.f, 0.f, 0.f};

    const int c0 = wave * 128 + lane;
    const int c1 = c0 + 64;
    const int r0 = c0 >> 2, e0 = (c0 & 3) * 8;
    const int r1 = c1 >> 2, e1 = (c1 & 3) * 8;
    const bf16* pa0 = A  + (size_t)(m0 + r0) * lda + e0;
    const bf16* pa1 = A  + (size_t)(m0 + r1) * lda + e1;
    const bf16* pb0 = BT + (size_t)(n0 + r0) * ldb + e0;
    const bf16* pb1 = BT + (size_t)(n0 + r1) * ldb + e1;
    const int lw0 = wave * 1024;
    const int lw1 = wave * 1024 + 512;

    const int arow = lane & 15;
    const int akq  = (lane >> 4) * 8;
    const int KT = K >> 5;

    auto STAGE = [&](int buf, int kt) {
        const int k0 = kt * 32;
        async16(pa0 + k0, &As[buf][lw0]);
        async16(pa1 + k0, &As[buf][lw1]);
        async16(pb0 + k0, &Bs[buf][lw0]);
        async16(pb1 + k0, &Bs[buf][lw1]);
    };
    auto COMPUTE = [&](int buf) {
        bf16x8 af[4], bfr[4];
#pragma unroll
        for (int i = 0; i < 4; ++i)
            af[i] = *(const bf16x8*)(&As[buf][(wm + i * 16 + arow) * 32 + akq]);
#pragma unroll
        for (int j = 0; j < 4; ++j)
            bfr[j] = *(const bf16x8*)(&Bs[buf][(wn + j * 16 + arow) * 32 + akq]);
#pragma unroll
        for (int i = 0; i < 4; ++i)
#pragma unroll
            for (int j = 0; j < 4; ++j)
                acc[i][j] = __builtin_amdgcn_mfma_f32_16x16x32_bf16(
                    af[i], bfr[j], acc[i][j], 0, 0, 0);
    };

    STAGE(0, 0);
    __syncthreads();

    for (int kt = 0; kt < KT; kt += 2) {
        STAGE(1, kt + 1);
        COMPUTE(0);
        __syncthreads();
        if (kt + 2 < KT) STAGE(0, kt + 2);
        COMPUTE(1);
        __syncthreads();
    }

    const int rbase = (lane >> 4) * 4;
    const int cbase = lane & 15;
#pragma unroll
    for (int i = 0; i < 4; ++i) {
        int row = m0 + wm + i * 16 + rbase;
#pragma unroll
        for (int j = 0; j < 4; ++j) {
            int col = n0 + wn + j * 16 + cbase;
#pragma unroll
            for (int r = 0; r < 4; ++r) {
                float v = acc[i][j][r];
                if (MODE == 0) {
                    Cf[(size_t)(row + r) * ldc + col] = v;
                } else if (MODE == 2) {
                    Cb[(size_t)(row + r) * ldc + col] = __float2bfloat16(v);
                } else {
                    if (col < DINNER) {
                        float v2 = v + bias[col];
                        float sp = (v2 > 20.f) ? v2 : log1pf(__expf(v2));
                        Cb[(size_t)(row + r) * ldc + col] = __float2bfloat16(sp);
                    } else {
                        Cf[(size_t)(row + r) * 128 + (col - DINNER)] = v;
                    }
                }
            }
        }
    }
}

// ---------------------------------------------------------------------------
// Causal depthwise conv (d_conv=4) + bias + SiLU. Reads bf16 x_inner =
// xz[:, :2048] (row stride 4096). One thread per (row, 8 channels).
// ---------------------------------------------------------------------------
__global__ __launch_bounds__(256)
void conv_silu(const bf16* __restrict__ xz, const float* __restrict__ conv_w,
               const float* __restrict__ conv_b, bf16* __restrict__ xc)
{
    int gid = blockIdx.x * 256 + threadIdx.x;   // NROWS * 256
    int d8  = gid & 255;
    int row = gid >> 8;
    int l   = row & (SEQ - 1);
    int d   = d8 * 8;
    const bf16* base = xz + (size_t)row * 4096 + d;
    float acc[8];
    float4 b0 = *(const float4*)(conv_b + d);
    float4 b1 = *(const float4*)(conv_b + d + 4);
    acc[0] = b0.x; acc[1] = b0.y; acc[2] = b0.z; acc[3] = b0.w;
    acc[4] = b1.x; acc[5] = b1.y; acc[6] = b1.z; acc[7] = b1.w;
    float w[8][4];
#pragma unroll
    for (int j = 0; j < 8; ++j) {
        float4 wv = *(const float4*)(conv_w + (size_t)(d + j) * 4);
        w[j][0] = wv.x; w[j][1] = wv.y; w[j][2] = wv.z; w[j][3] = wv.w;
    }
#pragma unroll
    for (int k = 0; k < 4; ++k) {
        if (l + k - 3 >= 0) {   // wave-uniform branch (row is block-uniform)
            bf16x8 v = *(const bf16x8*)(base + (ptrdiff_t)(k - 3) * 4096);
#pragma unroll
            for (int j = 0; j < 8; ++j)
                acc[j] = fmaf(b2f(v[j]), w[j][k], acc[j]);
        }
    }
    __align__(16) bf16 o[8];
#pragma unroll
    for (int j = 0; j < 8; ++j) {
        float s = acc[j] / (1.f + __expf(-acc[j]));
        o[j] = __float2bfloat16(s);
    }
    *(bf16x8*)(xc + (size_t)row * DINNER + d) = *(bf16x8*)o;
}

// ---------------------------------------------------------------------------
// Chunked selective scan, pass 1: per (b, chunk, d): P = prod(a_t), S = local h
// layout P/S[c][b][d][n].  dt/xc loads software-pipelined (prefetch t+1).
// ---------------------------------------------------------------------------
__global__ __launch_bounds__(256)
void scan_pass1(const bf16* __restrict__ xc, const bf16* __restrict__ dt,
                const float* __restrict__ bdt, const float* __restrict__ A_log,
                float* __restrict__ P, float* __restrict__ S)
{
    const int d  = blockIdx.x * 256 + threadIdx.x;
    const int c  = blockIdx.y;
    const int b  = blockIdx.z;
    const int t0 = c * CHUNK;
    __shared__ float bls[CHUNK][DSTATE];
    for (int i = threadIdx.x; i < CHUNK * DSTATE; i += 256) {
        int tl = i >> 4, col = i & 15;
        bls[tl][col] = bdt[(size_t)(b * SEQ + t0 + tl) * 128 + col];
    }
    __syncthreads();
    float acoef[16], h[16], p[16];
#pragma unroll
    for (int n = 0; n < 16; ++n) {
        acoef[n] = -__expf(A_log[(size_t)d * 16 + n]) * 1.44269504f;
        h[n] = 0.f; p[n] = 1.f;
    }
    size_t idx = (size_t)(b * SEQ + t0) * DINNER + d;
    bf16 dcur = dt[idx], xcur = xc[idx];
    for (int tl = 0; tl < CHUNK; ++tl) {
        bf16 dnext = dcur, xnext = xcur;
        if (tl + 1 < CHUNK) {                 // prefetch next timestep
            dnext = dt[idx + DINNER];
            xnext = xc[idx + DINNER];
        }
        float dtv = __bfloat162float(dcur);
        float xv  = __bfloat162float(xcur);
        float u = dtv * xv;
#pragma unroll
        for (int n = 0; n < 16; ++n) {
            float a = exp2f(dtv * acoef[n]);
            p[n] *= a;
            h[n] = fmaf(a, h[n], u * bls[tl][n]);
        }
        dcur = dnext; xcur = xnext; idx += DINNER;
    }
    size_t o = ((size_t)(c * NBATCH + b) * DINNER + d) * 16;
#pragma unroll
    for (int n = 0; n < 16; n += 4) {
        *(float4*)(P + o + n) = make_float4(p[n], p[n+1], p[n+2], p[n+3]);
        *(float4*)(S + o + n) = make_float4(h[n], h[n+1], h[n+2], h[n+3]);
    }
}

// ---------------------------------------------------------------------------
// Pass 2: sequential combine over chunks. One thread per (b,d,n).
// Hinit may alias P (each element read before overwrite, one owner thread).
// ---------------------------------------------------------------------------
__global__ __launch_bounds__(256)
void scan_pass2(const float* __restrict__ P, const float* __restrict__ S,
                float* __restrict__ Hinit)
{
    size_t idx = (size_t)blockIdx.x * 256 + threadIdx.x;
    const size_t stride = (size_t)NBATCH * DINNER * 16;
    float h = 0.f;
    for (int c = 0; c < NCHUNK; ++c) {
        size_t o = (size_t)c * stride + idx;
        float p = P[o];
        float s = S[o];
        Hinit[o] = h;
        h = fmaf(p, h, s);
    }
}

// ---------------------------------------------------------------------------
// Pass 3: replay chunk from true h_init; fuse y = scan + xc*D, * silu(z),
// cast bf16 into U (row stride 4096; reads z from cols 2048.. of same buffer).
// dt/xc/z loads software-pipelined (prefetch t+1).
// ---------------------------------------------------------------------------
__global__ __launch_bounds__(256)
void scan_pass3(const bf16* __restrict__ xc, const bf16* __restrict__ dt,
                const float* __restrict__ bdt, const float* __restrict__ A_log,
                const float* __restrict__ Hinit, const bf16* __restrict__ xzb,
                const float* __restrict__ Dp, bf16* __restrict__ U)
{
    const int d  = blockIdx.x * 256 + threadIdx.x;
    const int c  = blockIdx.y;
    const int b  = blockIdx.z;
    const int t0 = c * CHUNK;
    __shared__ float bls[CHUNK][DSTATE];
    __shared__ float cls[CHUNK][DSTATE];
    for (int i = threadIdx.x; i < CHUNK * 32; i += 256) {
        int tl = i >> 5, col = i & 31;
        float v = bdt[(size_t)(b * SEQ + t0 + tl) * 128 + col];
        if (col < 16) bls[tl][col] = v; else cls[tl][col - 16] = v;
    }
    __syncthreads();
    float acoef[16], h[16];
#pragma unroll
    for (int n = 0; n < 16; ++n)
        acoef[n] = -__expf(A_log[(size_t)d * 16 + n]) * 1.44269504f;
    size_t ho = ((size_t)(c * NBATCH + b) * DINNER + d) * 16;
#pragma unroll
    for (int n = 0; n < 16; n += 4) {
        float4 hv = *(const float4*)(Hinit + ho + n);
        h[n] = hv.x; h[n+1] = hv.y; h[n+2] = hv.z; h[n+3] = hv.w;
    }
    const float Dv = Dp[d];
    size_t idx  = (size_t)(b * SEQ + t0) * DINNER + d;
    size_t widx = (size_t)(b * SEQ + t0) * 4096 + d;   // U col d / z col 2048+d
    bf16 dcur = dt[idx], xcur = xc[idx], zcur = xzb[widx + DINNER];
    for (int tl = 0; tl < CHUNK; ++tl) {
        bf16 dnext = dcur, xnext = xcur, znext = zcur;
        if (tl + 1 < CHUNK) {                 // prefetch next timestep
            dnext = dt[idx + DINNER];
            xnext = xc[idx + DINNER];
            znext = xzb[widx + 4096 + DINNER];
        }
        float dtv = __bfloat162float(dcur);
        float xv  = __bfloat162float(xcur);
        float u = dtv * xv;
        float y = 0.f;
#pragma unroll
        for (int n = 0; n < 16; ++n) {
            float a = exp2f(dtv * acoef[n]);
            h[n] = fmaf(a, h[n], u * bls[tl][n]);
            y = fmaf(h[n], cls[tl][n], y);
        }
        float zv = __bfloat162float(zcur);
        float sz = zv / (1.f + __expf(-zv));
        float val = (y + xv * Dv) * sz;
        U[widx] = __float2bfloat16(val);
        dcur = dnext; xcur = xnext; zcur = znext;
        idx += DINNER; widx += 4096;
    }
}

// ---------------------------------------------------------------------------
extern "C" void kernel_launch(void* const* d_in, const int* in_sizes, int n_in,
                              void* d_out, int out_size, void* d_ws, size_t ws_size,
                              hipStream_t stream)
{
    const float* x      = (const float*)d_in[0];
    const float* W_in   = (const float*)d_in[1];
    const float* conv_w = (const float*)d_in[2];
    const float* conv_b = (const float*)d_in[3];
    const float* W_x    = (const float*)d_in[4];
    const float* W_dt   = (const float*)d_in[5];
    const float* b_dt   = (const float*)d_in[6];
    const float* W_out  = (const float*)d_in[7];
    const float* A_log  = (const float*)d_in[8];
    const float* Dp     = (const float*)d_in[9];
    float* out = (float*)d_out;

    // ---- workspace layout (~162 MB total, lifetime-checked aliasing) -------
    char* ws = (char*)d_ws;
    size_t off = 0;
    auto alloc = [&](size_t bytes) {
        char* p = ws + off;
        off += (bytes + 255) & ~(size_t)255;
        return (void*)p;
    };
    bf16*  xzb   = (bf16*) alloc((size_t)NROWS * 4096 * 2);   // 64 MB; x_inner half reused as U
    bf16*  xc    = (bf16*) alloc((size_t)NROWS * 2048 * 2);   // 32 MB
    bf16*  dtb   = (bf16*) alloc((size_t)NROWS * 2048 * 2);   // 32 MB; first 8 MB aliased by WinT
    float* bdt   = (float*)alloc((size_t)NROWS * 128 * 4);    //  4 MB
    bf16*  WcombT= (bf16*) alloc((size_t)2304 * 2048 * 2);    //  9 MB (W_dt^T ++ W_x^T pad; rows 2176+ garbage/discarded)
    bf16*  WoutT = (bf16*) alloc((size_t)1024 * 2048 * 2);    //  4 MB
    char*  scr   = (char*) alloc((size_t)16 << 20);           // 16 MB shared scratch
    // aliases (lifetimes verified):
    bf16*  WinT = (bf16*)dtb;          // used only by GEMM1; dt written later by merged GEMM
    bf16*  x_bf = (bf16*)scr;          // used only by GEMM1 (16 MB)
    float* Pb   = (float*)scr;         // written in pass1 (8 MB), after GEMM1
    float* Sb   = (float*)(scr + ((size_t)8 << 20));  // 8 MB
    float* Hb   = Pb;                  // pass2 writes Hinit in-place over P
    bf16*  U    = xzb;                 // pass3 writes U over dead x_inner half

    // ---- fused weight prep + x cast (one dispatch) -------------------------
    prep<<<18688, 256, 0, stream>>>(x, W_in, W_dt, W_x, W_out,
                                    x_bf, WinT, WcombT, WoutT);

    // xz = x @ W_in  (bf16 out, row stride 4096) — 256^2 tiles, 512 blocks
    gemm256<2><<<dim3(4096/256, NROWS/256), 512, 0, stream>>>(x_bf, 1024, WinT, 1024, nullptr, xzb, 4096, nullptr, 1024);
    // xc = silu(causal_conv(x_inner) + b)
    conv_silu<<<(NROWS * 256) / 256, 256, 0, stream>>>(xzb, conv_w, conv_b, xc);
    // merged: dt = softplus(xc @ W_dt + b_dt) [cols 0..2047, bf16]
    //         bdt = xc @ W_x                  [cols 2048..2175 -> fp32, ld 128]
    // N padded to 2304 (9 n-tiles); cols 2176+ discarded in epilogue
    gemm256<3><<<dim3(2304/256, NROWS/256), 512, 0, stream>>>(xc, 2048, WcombT, 2048, bdt, dtb, 2048, b_dt, 2048);
    // chunked selective scan
    scan_pass1<<<dim3(DINNER/256, NCHUNK, NBATCH), 256, 0, stream>>>(xc, dtb, bdt, A_log, Pb, Sb);
    scan_pass2<<<(NBATCH * DINNER * 16) / 256, 256, 0, stream>>>(Pb, Sb, Hb);
    scan_pass3<<<dim3(DINNER/256, NCHUNK, NBATCH), 256, 0, stream>>>(xc, dtb, bdt, A_log, Hb, xzb, Dp, U);
    // out = U @ W_out  (U row stride 4096) — 128^2 tiles (N=1024: 512 blocks)
    gemm_bt<0><<<dim3(1024/128, NROWS/128), 256, 0, stream>>>(U, 4096, WoutT, 2048, out, nullptr, 1024, nullptr, 2048);
}

// Round 6
// 724.617 us; speedup vs baseline: 1.0194x; 1.0194x over previous
//
#include <hip/hip_runtime.h>
#include <hip/hip_bf16.h>

typedef __hip_bfloat16 bf16;
typedef __attribute__((ext_vector_type(8))) short bf16x8;
typedef __attribute__((ext_vector_type(4))) float f32x4;

#define SEQ     2048
#define DMODEL  1024
#define DINNER  2048
#define NBATCH  4
#define NROWS   (NBATCH * SEQ)   // 8192
#define DSTATE  16
#define NCHUNK  16
#define CHUNK   128              // SEQ / NCHUNK

__device__ __forceinline__ float b2f(short s) {
    union { unsigned u; float f; } c;
    c.u = ((unsigned)(unsigned short)s) << 16;
    return c.f;
}

// async global->LDS direct copy, 16B per lane. LDS dest must be wave-uniform
// base (HW adds lane*16). CK-style addrspace casts via uintptr_t.
__device__ __forceinline__ void async16(const bf16* g, bf16* l) {
    auto gp = reinterpret_cast<const __attribute__((address_space(1))) unsigned*>(
        reinterpret_cast<uintptr_t>(g));
    auto lp = reinterpret_cast<__attribute__((address_space(3))) unsigned*>(
        reinterpret_cast<uintptr_t>(l));
    __builtin_amdgcn_global_load_lds(gp, lp, 16, 0, 0);
}

// ---------------------------------------------------------------------------
// Fused weight-prep kernel: one dispatch does all 4 transposes + the x cast.
//   [0,     8192): cast x (fp32->bf16), 4 elems/thread
//   [8192, 12288): W_in  (1024x4096) -> WinT  (4096x1024)
//   [12288,16384): W_dt  (2048x2048) -> WcombT rows 0..2047
//   [16384,16640): W_x   (2048x32)   -> WcombT rows 2048..2175 (pad 128)
//   [16640,18688): W_out (2048x1024) -> WoutT (1024x2048)
// WcombT is allocated with 2304 rows; rows 2176..2303 stay uninitialized and
// only feed MFMA frags whose outputs are discarded in the guarded epilogue.
// ---------------------------------------------------------------------------
__device__ __forceinline__ void transpose_tile(
    const float* __restrict__ W, bf16* __restrict__ WT,
    int K, int N, int Npad, int bx, int by)
{
    __shared__ float tile[32][33];
    const int tx = threadIdx.x & 31, ty = threadIdx.x >> 5;   // 32 x 8
    const int x = bx * 32 + tx;           // N index
#pragma unroll
    for (int i = 0; i < 32; i += 8) {
        int y = by * 32 + ty + i;         // K index
        tile[ty + i][tx] = (x < N && y < K) ? W[(size_t)y * N + x] : 0.f;
    }
    __syncthreads();
    const int k = by * 32 + tx;
#pragma unroll
    for (int i = 0; i < 32; i += 8) {
        int n = bx * 32 + ty + i;
        if (n < Npad && k < K)
            WT[(size_t)n * K + k] = __float2bfloat16(tile[tx][ty + i]);
    }
}

__global__ __launch_bounds__(256)
void prep(const float* __restrict__ x,     const float* __restrict__ W_in,
          const float* __restrict__ W_dt,  const float* __restrict__ W_x,
          const float* __restrict__ W_out, bf16* __restrict__ x_bf,
          bf16* __restrict__ WinT, bf16* __restrict__ WcombT,
          bf16* __restrict__ WoutT)
{
    const int bid = blockIdx.x;
    if (bid < 8192) {
        int i = bid * 256 + threadIdx.x;          // x cast: 8.4M elems / 4
        float4 v = *(const float4*)(x + (size_t)i * 4);
        __align__(8) bf16 o[4] = { __float2bfloat16(v.x), __float2bfloat16(v.y),
                                   __float2bfloat16(v.z), __float2bfloat16(v.w) };
        *(uint2*)(x_bf + (size_t)i * 4) = *(uint2*)o;
    } else if (bid < 12288) {
        int t = bid - 8192;                       // W_in: 128 x 32 tiles
        transpose_tile(W_in, WinT, 1024, 4096, 4096, t & 127, t >> 7);
    } else if (bid < 16384) {
        int t = bid - 12288;                      // W_dt: 64 x 64 tiles
        transpose_tile(W_dt, WcombT, 2048, 2048, 2048, t & 63, t >> 6);
    } else if (bid < 16640) {
        int t = bid - 16384;                      // W_x: 4 x 64 tiles
        transpose_tile(W_x, WcombT + (size_t)2048 * 2048, 2048, 32, 128,
                       t & 3, t >> 2);
    } else {
        int t = bid - 16640;                      // W_out: 32 x 64 tiles
        transpose_tile(W_out, WoutT, 2048, 1024, 1024, t & 31, t >> 5);
    }
}

// ---------------------------------------------------------------------------
// 256x256 GEMM: C[M,N] = A[M,K] @ B^T[N,K]  (bf16 in, fp32 accum).
// 2-phase double-buffered global_load_lds at 256^2/BK=64, 512 threads
// (8 waves, 2M x 4N, 128x64 output each, 8x4 MFMA frags, 64 MFMA/wave/tile).
// R13 = R11 design, third attempt (two container-level failures, full audit
// found no OOB/hang mechanism; R10 same structure minus swizzle ran clean).
// Defensive change: __launch_bounds__(512, 1) — honest occupancy (128 KB LDS
// means 1 block/CU; the old "2" promised an impossible residency).
// T2 both-sides XOR swizzle (rule #21). R10 post-mortem: BK=64 row stride =
// 128 B = 32 banks -> frag read (16 lanes, 16 rows, same 16B col) was a
// 16-WAY bank conflict — SQ_LDS_BANK_CONFLICT 2.1e7, ~1600 LDS-cyc vs 310
// MFMA-cyc per wave per tile at 1 block/CU. Fix: per row, 16B-slot s stored
// at s ^ (row&7). LDS dest stays LINEAR (chunk c -> byte c*16, as
// global_load_lds requires); the GLOBAL source is pre-permuted per-lane
// (folded into pa[]/pb[], zero loop cost); reads apply the same involution
// (row&7 == lane&7 since wm/wn/i*16 are multiples of 16). Fixed-s reads then
// hit all 8 bank-groups 2-way (free, m136).
// MODE 2: store bf16.  MODE 3: merged dt/bdt epilogue (guarded for N-pad).
// ---------------------------------------------------------------------------
template <int MODE>
__global__ __launch_bounds__(512, 1)
void gemm256(const bf16* __restrict__ A, int lda, const bf16* __restrict__ BT,
             int ldb, float* __restrict__ Cf, bf16* __restrict__ Cb, int ldc,
             const float* __restrict__ bias, int K)
{
    __shared__ __align__(16) bf16 As[2][256 * 64];
    __shared__ __align__(16) bf16 Bs[2][256 * 64];
    const int tid  = threadIdx.x;
    const int lane = tid & 63;
    const int wave = tid >> 6;          // 0..7

    // ---- group-of-8 m-panel swizzle (L2/L3 reuse) ----
    const int gx = gridDim.x, gy = gridDim.y;
    int lin = blockIdx.y * gx + blockIdx.x;
    const int per = 8 * gx;
    int g   = lin / per;
    int rem = lin - g * per;
    int rows = min(8, gy - g * 8);
    const int by = g * 8 + rem % rows;
    const int bx = rem / rows;

    const int m0 = by * 256;
    const int n0 = bx * 256;
    const int wm = (wave >> 2) * 128;   // 0 or 128
    const int wn = (wave & 3) * 64;     // 0,64,128,192

    f32x4 acc[8][4];
#pragma unroll
    for (int i = 0; i < 8; ++i)
#pragma unroll
        for (int j = 0; j < 4; ++j) acc[i][j] = (f32x4){0.f, 0.f, 0.f, 0.f};

    // staging: tile = 256 rows x 64 cols bf16 = 2048 16B-chunks. LDS is
    // LINEAR in chunk c (byte c*16). Chunk c holds global (row = c>>3,
    // slot = (c&7) ^ (row&7)) — the inverse swizzle applied to the SOURCE.
    // issue q in [0,4): chunk = q*512 + tid; wave's 64 lanes are consecutive
    // chunks -> LDS base q*4096 + wave*512 elems (wave-uniform, HW +lane*16B).
    const bf16* pa[4];
    const bf16* pb[4];
#pragma unroll
    for (int q = 0; q < 4; ++q) {
        int c = q * 512 + tid;
        int r = c >> 3;
        int sg = (c & 7) ^ (r & 7);     // pre-swizzled global 16B-slot
        pa[q] = A  + (size_t)(m0 + r) * lda + sg * 8;
        pb[q] = BT + (size_t)(n0 + r) * ldb + sg * 8;
    }

    const int arow = lane & 15;
    // swizzled slot*8 elems for ks=0: slot = (lane>>4) ^ (lane&7); ks=1 flips
    // bit2 of the slot == XOR 32 on the elem offset.
    const int sw0 = (((lane >> 4) ^ (lane & 7))) * 8;
    const int KT = K >> 6;              // 16 (K=1024) or 32 (K=2048): even

    auto STAGE = [&](int buf, int kt) {
        const int k0 = kt * 64;
#pragma unroll
        for (int q = 0; q < 4; ++q)
            async16(pa[q] + k0, &As[buf][q * 4096 + wave * 512]);
#pragma unroll
        for (int q = 0; q < 4; ++q)
            async16(pb[q] + k0, &Bs[buf][q * 4096 + wave * 512]);
    };
    auto COMPUTE = [&](int buf) {
#pragma unroll
        for (int ks = 0; ks < 2; ++ks) {
            const int ko = sw0 ^ (ks << 5);   // swizzled k-offset (elems)
            bf16x8 bfr[4];
#pragma unroll
            for (int j = 0; j < 4; ++j)
                bfr[j] = *(const bf16x8*)(
                    &Bs[buf][(wn + j * 16 + arow) * 64 + ko]);
#pragma unroll
            for (int i = 0; i < 8; ++i) {
                bf16x8 af = *(const bf16x8*)(
                    &As[buf][(wm + i * 16 + arow) * 64 + ko]);
#pragma unroll
                for (int j = 0; j < 4; ++j)
                    acc[i][j] = __builtin_amdgcn_mfma_f32_16x16x32_bf16(
                        af, bfr[j], acc[i][j], 0, 0, 0);
            }
        }
    };

    // prologue: stage tile 0; __syncthreads() = vmcnt(0)+barrier publishes it
    STAGE(0, 0);
    __syncthreads();

    for (int kt = 0; kt < KT; kt += 2) {
        STAGE(1, kt + 1);                // issue-ahead into buf1
        COMPUTE(0);
        __syncthreads();                 // buf1 landed; all done reading buf0
        if (kt + 2 < KT) STAGE(0, kt + 2);
        COMPUTE(1);
        __syncthreads();                 // buf0 landed; all done reading buf1
    }

    // epilogue: C/D layout col = lane&15, row = (lane>>4)*4 + reg
    const int rbase = (lane >> 4) * 4;
    const int cbase = lane & 15;
#pragma unroll
    for (int i = 0; i < 8; ++i) {
        int row = m0 + wm + i * 16 + rbase;
#pragma unroll
        for (int j = 0; j < 4; ++j) {
            int col = n0 + wn + j * 16 + cbase;
#pragma unroll
            for (int r = 0; r < 4; ++r) {
                float v = acc[i][j][r];
                if (MODE == 2) {
                    Cb[(size_t)(row + r) * ldc + col] = __float2bfloat16(v);
                } else {   // MODE 3: dt cols [0,2048), bdt [2048,2176), pad discard
                    if (col < DINNER) {
                        float v2 = v + bias[col];
                        float sp = (v2 > 20.f) ? v2 : log1pf(__expf(v2));
                        Cb[(size_t)(row + r) * ldc + col] = __float2bfloat16(sp);
                    } else if (col < DINNER + 128) {
                        Cf[(size_t)(row + r) * 128 + (col - DINNER)] = v;
                    }
                }
            }
        }
    }
}

// ---------------------------------------------------------------------------
// 128x128 GEMM (kept for GEMM_out, N=1024: 512 blocks vs 128 at 256^2).
// Double-buffered global_load_lds, issue-ahead, 1 barrier/tile.
// Same both-sides swizzle, 4 slots/row (BK=32, 64B stride was 8-way):
// slot s stored at s ^ ((row>>1)&3). MODE 0: store fp32.
// ---------------------------------------------------------------------------
template <int MODE>
__global__ __launch_bounds__(256, 2)
void gemm_bt(const bf16* __restrict__ A, int lda, const bf16* __restrict__ BT,
             int ldb, float* __restrict__ Cf, bf16* __restrict__ Cb, int ldc,
             const float* __restrict__ bias, int K)
{
    __shared__ __align__(16) bf16 As[2][128 * 32];
    __shared__ __align__(16) bf16 Bs[2][128 * 32];
    const int tid  = threadIdx.x;
    const int lane = tid & 63;
    const int wave = tid >> 6;

    const int gx = gridDim.x, gy = gridDim.y;
    int lin = blockIdx.y * gx + blockIdx.x;
    const int per = 8 * gx;
    int g   = lin / per;
    int rem = lin - g * per;
    int rows = min(8, gy - g * 8);
    const int by = g * 8 + rem % rows;
    const int bx = rem / rows;

    const int m0 = by * 128;
    const int n0 = bx * 128;
    const int wm = (wave & 1) * 64;
    const int wn = (wave >> 1) * 64;

    f32x4 acc[4][4];
#pragma unroll
    for (int i = 0; i < 4; ++i)
#pragma unroll
        for (int j = 0; j < 4; ++j) acc[i][j] = (f32x4){0.f, 0.f, 0.f, 0.f};

    // chunk c -> row c>>2; holds global slot (c&3) ^ ((row>>1)&3)
    const int c0 = wave * 128 + lane;
    const int c1 = c0 + 64;
    const int r0 = c0 >> 2, s0 = (c0 & 3) ^ ((r0 >> 1) & 3);
    const int r1 = c1 >> 2, s1 = (c1 & 3) ^ ((r1 >> 1) & 3);
    const bf16* pa0 = A  + (size_t)(m0 + r0) * lda + s0 * 8;
    const bf16* pa1 = A  + (size_t)(m0 + r1) * lda + s1 * 8;
    const bf16* pb0 = BT + (size_t)(n0 + r0) * ldb + s0 * 8;
    const bf16* pb1 = BT + (size_t)(n0 + r1) * ldb + s1 * 8;
    const int lw0 = wave * 1024;
    const int lw1 = wave * 1024 + 512;

    const int arow = lane & 15;
    // read slot = (lane>>4) ^ ((row>>1)&3); row bits 1-2 come from arow
    const int swb = (((lane >> 4) ^ ((arow >> 1) & 3))) * 8;
    const int KT = K >> 5;

    auto STAGE = [&](int buf, int kt) {
        const int k0 = kt * 32;
        async16(pa0 + k0, &As[buf][lw0]);
        async16(pa1 + k0, &As[buf][lw1]);
        async16(pb0 + k0, &Bs[buf][lw0]);
        async16(pb1 + k0, &Bs[buf][lw1]);
    };
    auto COMPUTE = [&](int buf) {
        bf16x8 af[4], bfr[4];
#pragma unroll
        for (int i = 0; i < 4; ++i)
            af[i] = *(const bf16x8*)(&As[buf][(wm + i * 16 + arow) * 32 + swb]);
#pragma unroll
        for (int j = 0; j < 4; ++j)
            bfr[j] = *(const bf16x8*)(&Bs[buf][(wn + j * 16 + arow) * 32 + swb]);
#pragma unroll
        for (int i = 0; i < 4; ++i)
#pragma unroll
            for (int j = 0; j < 4; ++j)
                acc[i][j] = __builtin_amdgcn_mfma_f32_16x16x32_bf16(
                    af[i], bfr[j], acc[i][j], 0, 0, 0);
    };

    STAGE(0, 0);
    __syncthreads();

    for (int kt = 0; kt < KT; kt += 2) {
        STAGE(1, kt + 1);
        COMPUTE(0);
        __syncthreads();
        if (kt + 2 < KT) STAGE(0, kt + 2);
        COMPUTE(1);
        __syncthreads();
    }

    const int rbase = (lane >> 4) * 4;
    const int cbase = lane & 15;
#pragma unroll
    for (int i = 0; i < 4; ++i) {
        int row = m0 + wm + i * 16 + rbase;
#pragma unroll
        for (int j = 0; j < 4; ++j) {
            int col = n0 + wn + j * 16 + cbase;
#pragma unroll
            for (int r = 0; r < 4; ++r) {
                float v = acc[i][j][r];
                if (MODE == 0) {
                    Cf[(size_t)(row + r) * ldc + col] = v;
                } else if (MODE == 2) {
                    Cb[(size_t)(row + r) * ldc + col] = __float2bfloat16(v);
                } else {
                    if (col < DINNER) {
                        float v2 = v + bias[col];
                        float sp = (v2 > 20.f) ? v2 : log1pf(__expf(v2));
                        Cb[(size_t)(row + r) * ldc + col] = __float2bfloat16(sp);
                    } else {
                        Cf[(size_t)(row + r) * 128 + (col - DINNER)] = v;
                    }
                }
            }
        }
    }
}

// ---------------------------------------------------------------------------
// Causal depthwise conv (d_conv=4) + bias + SiLU. Reads bf16 x_inner =
// xz[:, :2048] (row stride 4096). One thread per (row, 8 channels).
// ---------------------------------------------------------------------------
__global__ __launch_bounds__(256)
void conv_silu(const bf16* __restrict__ xz, const float* __restrict__ conv_w,
               const float* __restrict__ conv_b, bf16* __restrict__ xc)
{
    int gid = blockIdx.x * 256 + threadIdx.x;   // NROWS * 256
    int d8  = gid & 255;
    int row = gid >> 8;
    int l   = row & (SEQ - 1);
    int d   = d8 * 8;
    const bf16* base = xz + (size_t)row * 4096 + d;
    float acc[8];
    float4 b0 = *(const float4*)(conv_b + d);
    float4 b1 = *(const float4*)(conv_b + d + 4);
    acc[0] = b0.x; acc[1] = b0.y; acc[2] = b0.z; acc[3] = b0.w;
    acc[4] = b1.x; acc[5] = b1.y; acc[6] = b1.z; acc[7] = b1.w;
    float w[8][4];
#pragma unroll
    for (int j = 0; j < 8; ++j) {
        float4 wv = *(const float4*)(conv_w + (size_t)(d + j) * 4);
        w[j][0] = wv.x; w[j][1] = wv.y; w[j][2] = wv.z; w[j][3] = wv.w;
    }
#pragma unroll
    for (int k = 0; k < 4; ++k) {
        if (l + k - 3 >= 0) {   // wave-uniform branch (row is block-uniform)
            bf16x8 v = *(const bf16x8*)(base + (ptrdiff_t)(k - 3) * 4096);
#pragma unroll
            for (int j = 0; j < 8; ++j)
                acc[j] = fmaf(b2f(v[j]), w[j][k], acc[j]);
        }
    }
    __align__(16) bf16 o[8];
#pragma unroll
    for (int j = 0; j < 8; ++j) {
        float s = acc[j] / (1.f + __expf(-acc[j]));
        o[j] = __float2bfloat16(s);
    }
    *(bf16x8*)(xc + (size_t)row * DINNER + d) = *(bf16x8*)o;
}

// ---------------------------------------------------------------------------
// Chunked selective scan, pass 1: per (b, chunk, d): P = prod(a_t), S = local h
// layout P/S[c][b][d][n].  dt/xc loads software-pipelined (prefetch t+1).
// ---------------------------------------------------------------------------
__global__ __launch_bounds__(256)
void scan_pass1(const bf16* __restrict__ xc, const bf16* __restrict__ dt,
                const float* __restrict__ bdt, const float* __restrict__ A_log,
                float* __restrict__ P, float* __restrict__ S)
{
    const int d  = blockIdx.x * 256 + threadIdx.x;
    const int c  = blockIdx.y;
    const int b  = blockIdx.z;
    const int t0 = c * CHUNK;
    __shared__ float bls[CHUNK][DSTATE];
    for (int i = threadIdx.x; i < CHUNK * DSTATE; i += 256) {
        int tl = i >> 4, col = i & 15;
        bls[tl][col] = bdt[(size_t)(b * SEQ + t0 + tl) * 128 + col];
    }
    __syncthreads();
    float acoef[16], h[16], p[16];
#pragma unroll
    for (int n = 0; n < 16; ++n) {
        acoef[n] = -__expf(A_log[(size_t)d * 16 + n]) * 1.44269504f;
        h[n] = 0.f; p[n] = 1.f;
    }
    size_t idx = (size_t)(b * SEQ + t0) * DINNER + d;
    bf16 dcur = dt[idx], xcur = xc[idx];
    for (int tl = 0; tl < CHUNK; ++tl) {
        bf16 dnext = dcur, xnext = xcur;
        if (tl + 1 < CHUNK) {                 // prefetch next timestep
            dnext = dt[idx + DINNER];
            xnext = xc[idx + DINNER];
        }
        float dtv = __bfloat162float(dcur);
        float xv  = __bfloat162float(xcur);
        float u = dtv * xv;
#pragma unroll
        for (int n = 0; n < 16; ++n) {
            float a = exp2f(dtv * acoef[n]);
            p[n] *= a;
            h[n] = fmaf(a, h[n], u * bls[tl][n]);
        }
        dcur = dnext; xcur = xnext; idx += DINNER;
    }
    size_t o = ((size_t)(c * NBATCH + b) * DINNER + d) * 16;
#pragma unroll
    for (int n = 0; n < 16; n += 4) {
        *(float4*)(P + o + n) = make_float4(p[n], p[n+1], p[n+2], p[n+3]);
        *(float4*)(S + o + n) = make_float4(h[n], h[n+1], h[n+2], h[n+3]);
    }
}

// ---------------------------------------------------------------------------
// Pass 2: sequential combine over chunks. One thread per (b,d,n).
// Hinit may alias P (each element read before overwrite, one owner thread).
// ---------------------------------------------------------------------------
__global__ __launch_bounds__(256)
void scan_pass2(const float* __restrict__ P, const float* __restrict__ S,
                float* __restrict__ Hinit)
{
    size_t idx = (size_t)blockIdx.x * 256 + threadIdx.x;
    const size_t stride = (size_t)NBATCH * DINNER * 16;
    float h = 0.f;
    for (int c = 0; c < NCHUNK; ++c) {
        size_t o = (size_t)c * stride + idx;
        float p = P[o];
        float s = S[o];
        Hinit[o] = h;
        h = fmaf(p, h, s);
    }
}

// ---------------------------------------------------------------------------
// Pass 3: replay chunk from true h_init; fuse y = scan + xc*D, * silu(z),
// cast bf16 into U (row stride 4096; reads z from cols 2048.. of same buffer).
// dt/xc/z loads software-pipelined (prefetch t+1).
// ---------------------------------------------------------------------------
__global__ __launch_bounds__(256)
void scan_pass3(const bf16* __restrict__ xc, const bf16* __restrict__ dt,
                const float* __restrict__ bdt, const float* __restrict__ A_log,
                const float* __restrict__ Hinit, const bf16* __restrict__ xzb,
                const float* __restrict__ Dp, bf16* __restrict__ U)
{
    const int d  = blockIdx.x * 256 + threadIdx.x;
    const int c  = blockIdx.y;
    const int b  = blockIdx.z;
    const int t0 = c * CHUNK;
    __shared__ float bls[CHUNK][DSTATE];
    __shared__ float cls[CHUNK][DSTATE];
    for (int i = threadIdx.x; i < CHUNK * 32; i += 256) {
        int tl = i >> 5, col = i & 31;
        float v = bdt[(size_t)(b * SEQ + t0 + tl) * 128 + col];
        if (col < 16) bls[tl][col] = v; else cls[tl][col - 16] = v;
    }
    __syncthreads();
    float acoef[16], h[16];
#pragma unroll
    for (int n = 0; n < 16; ++n)
        acoef[n] = -__expf(A_log[(size_t)d * 16 + n]) * 1.44269504f;
    size_t ho = ((size_t)(c * NBATCH + b) * DINNER + d) * 16;
#pragma unroll
    for (int n = 0; n < 16; n += 4) {
        float4 hv = *(const float4*)(Hinit + ho + n);
        h[n] = hv.x; h[n+1] = hv.y; h[n+2] = hv.z; h[n+3] = hv.w;
    }
    const float Dv = Dp[d];
    size_t idx  = (size_t)(b * SEQ + t0) * DINNER + d;
    size_t widx = (size_t)(b * SEQ + t0) * 4096 + d;   // U col d / z col 2048+d
    bf16 dcur = dt[idx], xcur = xc[idx], zcur = xzb[widx + DINNER];
    for (int tl = 0; tl < CHUNK; ++tl) {
        bf16 dnext = dcur, xnext = xcur, znext = zcur;
        if (tl + 1 < CHUNK) {                 // prefetch next timestep
            dnext = dt[idx + DINNER];
            xnext = xc[idx + DINNER];
            znext = xzb[widx + 4096 + DINNER];
        }
        float dtv = __bfloat162float(dcur);
        float xv  = __bfloat162float(xcur);
        float u = dtv * xv;
        float y = 0.f;
#pragma unroll
        for (int n = 0; n < 16; ++n) {
            float a = exp2f(dtv * acoef[n]);
            h[n] = fmaf(a, h[n], u * bls[tl][n]);
            y = fmaf(h[n], cls[tl][n], y);
        }
        float zv = __bfloat162float(zcur);
        float sz = zv / (1.f + __expf(-zv));
        float val = (y + xv * Dv) * sz;
        U[widx] = __float2bfloat16(val);
        dcur = dnext; xcur = xnext; zcur = znext;
        idx += DINNER; widx += 4096;
    }
}

// ---------------------------------------------------------------------------
extern "C" void kernel_launch(void* const* d_in, const int* in_sizes, int n_in,
                              void* d_out, int out_size, void* d_ws, size_t ws_size,
                              hipStream_t stream)
{
    const float* x      = (const float*)d_in[0];
    const float* W_in   = (const float*)d_in[1];
    const float* conv_w = (const float*)d_in[2];
    const float* conv_b = (const float*)d_in[3];
    const float* W_x    = (const float*)d_in[4];
    const float* W_dt   = (const float*)d_in[5];
    const float* b_dt   = (const float*)d_in[6];
    const float* W_out  = (const float*)d_in[7];
    const float* A_log  = (const float*)d_in[8];
    const float* Dp     = (const float*)d_in[9];
    float* out = (float*)d_out;

    // ---- workspace layout (~162 MB total, lifetime-checked aliasing) -------
    char* ws = (char*)d_ws;
    size_t off = 0;
    auto alloc = [&](size_t bytes) {
        char* p = ws + off;
        off += (bytes + 255) & ~(size_t)255;
        return (void*)p;
    };
    bf16*  xzb   = (bf16*) alloc((size_t)NROWS * 4096 * 2);   // 64 MB; x_inner half reused as U
    bf16*  xc    = (bf16*) alloc((size_t)NROWS * 2048 * 2);   // 32 MB
    bf16*  dtb   = (bf16*) alloc((size_t)NROWS * 2048 * 2);   // 32 MB; first 8 MB aliased by WinT
    float* bdt   = (float*)alloc((size_t)NROWS * 128 * 4);    //  4 MB
    bf16*  WcombT= (bf16*) alloc((size_t)2304 * 2048 * 2);    //  9 MB (W_dt^T ++ W_x^T pad; rows 2176+ garbage/discarded)
    bf16*  WoutT = (bf16*) alloc((size_t)1024 * 2048 * 2);    //  4 MB
    char*  scr   = (char*) alloc((size_t)16 << 20);           // 16 MB shared scratch
    // aliases (lifetimes verified):
    bf16*  WinT = (bf16*)dtb;          // used only by GEMM1; dt written later by merged GEMM
    bf16*  x_bf = (bf16*)scr;          // used only by GEMM1 (16 MB)
    float* Pb   = (float*)scr;         // written in pass1 (8 MB), after GEMM1
    float* Sb   = (float*)(scr + ((size_t)8 << 20));  // 8 MB
    float* Hb   = Pb;                  // pass2 writes Hinit in-place over P
    bf16*  U    = xzb;                 // pass3 writes U over dead x_inner half

    // ---- fused weight prep + x cast (one dispatch) -------------------------
    prep<<<18688, 256, 0, stream>>>(x, W_in, W_dt, W_x, W_out,
                                    x_bf, WinT, WcombT, WoutT);

    // xz = x @ W_in  (bf16 out, row stride 4096) — 256^2 tiles, 512 blocks
    gemm256<2><<<dim3(4096/256, NROWS/256), 512, 0, stream>>>(x_bf, 1024, WinT, 1024, nullptr, xzb, 4096, nullptr, 1024);
    // xc = silu(causal_conv(x_inner) + b)
    conv_silu<<<(NROWS * 256) / 256, 256, 0, stream>>>(xzb, conv_w, conv_b, xc);
    // merged: dt = softplus(xc @ W_dt + b_dt) [cols 0..2047, bf16]
    //         bdt = xc @ W_x                  [cols 2048..2175 -> fp32, ld 128]
    // N padded to 2304 (9 n-tiles); cols 2176+ discarded in epilogue
    gemm256<3><<<dim3(2304/256, NROWS/256), 512, 0, stream>>>(xc, 2048, WcombT, 2048, bdt, dtb, 2048, b_dt, 2048);
    // chunked selective scan
    scan_pass1<<<dim3(DINNER/256, NCHUNK, NBATCH), 256, 0, stream>>>(xc, dtb, bdt, A_log, Pb, Sb);
    scan_pass2<<<(NBATCH * DINNER * 16) / 256, 256, 0, stream>>>(Pb, Sb, Hb);
    scan_pass3<<<dim3(DINNER/256, NCHUNK, NBATCH), 256, 0, stream>>>(xc, dtb, bdt, A_log, Hb, xzb, Dp, U);
    // out = U @ W_out  (U row stride 4096) — 128^2 tiles (N=1024: 512 blocks)
    gemm_bt<0><<<dim3(1024/128, NROWS/128), 256, 0, stream>>>(U, 4096, WoutT, 2048, out, nullptr, 1024, nullptr, 2048);
}